// Round 4
// baseline (705.178 us; speedup 1.0000x reference)
//
#include <hip/hip_runtime.h>
#include <math.h>

#define BATCH  32
#define NPTS   8192
#define NGROUP 512
#define MSIZE  32

#define FPS_THREADS 512
#define SXYZ_FLOATS (NPTS * 3)
#define DYN_LDS_BYTES (SXYZ_FLOATS * 4)

// ---- DPP helpers (CTRL compile-time const) --------------------------------
// f32 max: bound_ctrl=true -> masked-off lanes read 0; fmax(x,0)=x for x>=0.
template<int CTRL>
__device__ __forceinline__ float dpp_max_f32(float x) {
    int o = __builtin_amdgcn_update_dpp(0, __float_as_int(x), CTRL, 0xF, 0xF, true);
    float f = __int_as_float(o);
    return x > f ? x : f;
}
// u32 min: stages 0xB1/0x4E/0x141/0x140 are full permutations (all sources
// valid). 0x142/0x143 corrupt non-receiving rows to min(x,0)=0, but lane 63's
// reduction chain only consumes valid sources (rows 2,3 + lane31), so the
// final value at lane 63 is the exact wave min.
template<int CTRL>
__device__ __forceinline__ unsigned dpp_min_u32(unsigned x) {
    unsigned o = (unsigned)__builtin_amdgcn_update_dpp(0, (int)x, CTRL, 0xF, 0xF, true);
    return o < x ? o : x;
}
template<int CTRL>
__device__ __forceinline__ unsigned long long dpp_min_u64(unsigned long long k) {
    int lo2 = __builtin_amdgcn_update_dpp(0, (int)(unsigned)k,        CTRL, 0xF, 0xF, true);
    int hi2 = __builtin_amdgcn_update_dpp(0, (int)(unsigned)(k >> 32), CTRL, 0xF, 0xF, true);
    unsigned long long k2 = (((unsigned long long)(unsigned)hi2) << 32) | (unsigned)lo2;
    return k2 < k ? k2 : k;
}

// ---------------------------------------------------------------------------
// FPS: one block/batch, 512 threads (8 waves, 2/SIMD), 16 pts/thread in
// registers (no u64 keys -> fits VGPR budget). Per step:
//   phase 1: dist update (bit-exact numpy: (dx^2+dy^2)+dz^2, contract off,
//            v_min) -> per-thread max3 tree -> f32 DPP wave max -> LDS partial
//   barrier; all waves compute gmax; ONLY waves with wmax==gmax reconstruct
//   min index among ties (exact np.argmax first-occurrence, incl. cross-wave
//   ties) and ds_min_u32 it; barrier; read winner.
// Partials & winner slot double-buffered; winner slot pre-reset one step ahead.
// ---------------------------------------------------------------------------
__global__ __launch_bounds__(FPS_THREADS, 2)
void fps_kernel(const float* __restrict__ xyz,
                float* __restrict__ out_center,
                float* __restrict__ out_fps)
{
#pragma clang fp contract(off)
    extern __shared__ float sxyz[];                  // [24576]
    __shared__ float        pmax[2][8];
    __shared__ unsigned int sidx[2];

    const int b    = blockIdx.x;
    const int t    = threadIdx.x;
    const int lane = t & 63;
    const int wid  = t >> 6;
    const float* bp = xyz + (size_t)b * NPTS * 3;
    const float4* bp4 = reinterpret_cast<const float4*>(bp);
    float4* s4 = reinterpret_cast<float4*>(sxyz);

    // thread t owns pts gidx = c*2048 + t*4 + k, c in [0,4), k in [0,4)
    float px[16], py[16], pz[16], dist[16];
    #pragma unroll
    for (int c = 0; c < 4; ++c) {
        int f4 = c * 1536 + t * 3;
        float4 A = bp4[f4 + 0];
        float4 B = bp4[f4 + 1];
        float4 C = bp4[f4 + 2];
        s4[f4 + 0] = A; s4[f4 + 1] = B; s4[f4 + 2] = C;
        float xs[4] = {A.x, A.w, B.z, C.y};
        float ys[4] = {A.y, B.x, B.w, C.z};
        float zs[4] = {A.z, B.y, C.x, C.w};
        #pragma unroll
        for (int k = 0; k < 4; ++k) {
            int j = c * 4 + k;
            px[j] = xs[k]; py[j] = ys[k]; pz[j] = zs[k];
            dist[j] = INFINITY;
        }
    }
    if (t == 0) { sidx[0] = 0xFFFFFFFFu; sidx[1] = 0xFFFFFFFFu; }
    __syncthreads();   // sxyz + sidx visible

    if (t == 0) {
        out_fps[(size_t)b * NGROUP] = 0.0f;
        out_center[(size_t)(b * NGROUP) * 3 + 0] = sxyz[0];
        out_center[(size_t)(b * NGROUP) * 3 + 1] = sxyz[1];
        out_center[(size_t)(b * NGROUP) * 3 + 2] = sxyz[2];
    }

    const int tbase = t * 4;
    int last = 0;
    for (int g = 1; g < NGROUP; ++g) {
        const int p = g & 1, q = p ^ 1;
        float lx = sxyz[last*3 + 0];     // broadcast LDS reads
        float ly = sxyz[last*3 + 1];
        float lz = sxyz[last*3 + 2];

        // dist update, numpy order, no fma
        #pragma unroll
        for (int j = 0; j < 16; ++j) {
            float dx = px[j] - lx;
            float dy = py[j] - ly;
            float dz = pz[j] - lz;
            float d  = (dx*dx + dy*dy) + dz*dz;
            dist[j] = dist[j] < d ? dist[j] : d;
        }
        // per-thread f32 max tree (max is exact & order-free)
        float m01 = fmaxf(fmaxf(dist[0],  dist[1]),  fmaxf(dist[2],  dist[3]));
        float m23 = fmaxf(fmaxf(dist[4],  dist[5]),  fmaxf(dist[6],  dist[7]));
        float m45 = fmaxf(fmaxf(dist[8],  dist[9]),  fmaxf(dist[10], dist[11]));
        float m67 = fmaxf(fmaxf(dist[12], dist[13]), fmaxf(dist[14], dist[15]));
        float m = fmaxf(fmaxf(m01, m23), fmaxf(m45, m67));
        // f32 DPP wave max -> lane 63
        m = dpp_max_f32<0xB1>(m);     // quad_perm xor1
        m = dpp_max_f32<0x4E>(m);     // quad_perm xor2
        m = dpp_max_f32<0x141>(m);    // row_half_mirror
        m = dpp_max_f32<0x140>(m);    // row_mirror
        m = dpp_max_f32<0x142>(m);    // row_bcast15
        m = dpp_max_f32<0x143>(m);    // row_bcast31
        float wmax = __int_as_float(__builtin_amdgcn_readlane(__float_as_int(m), 63));
        if (lane == 63) pmax[p][wid] = wmax;
        __syncthreads();              // barrier 1

        // block max (broadcast reads, exact)
        float gmax = fmaxf(
            fmaxf(fmaxf(pmax[p][0], pmax[p][1]), fmaxf(pmax[p][2], pmax[p][3])),
            fmaxf(fmaxf(pmax[p][4], pmax[p][5]), fmaxf(pmax[p][6], pmax[p][7])));
        if (t == 0) sidx[q] = 0xFFFFFFFFu;   // pre-reset for step g+1

        if (wmax == gmax) {           // wave-uniform branch: winning wave(s) only
            unsigned c0[16];
            #pragma unroll
            for (int j = 0; j < 16; ++j) {
                unsigned gj = (unsigned)((j >> 2) * 2048 + tbase + (j & 3));
                c0[j] = (dist[j] == gmax) ? gj : 0xFFFFFFFFu;
            }
            #pragma unroll
            for (int s = 8; s >= 1; s >>= 1)
                #pragma unroll
                for (int i = 0; i < s; ++i)
                    c0[i] = c0[i] < c0[i+s] ? c0[i] : c0[i+s];
            unsigned mi = c0[0];
            mi = dpp_min_u32<0xB1>(mi);
            mi = dpp_min_u32<0x4E>(mi);
            mi = dpp_min_u32<0x141>(mi);
            mi = dpp_min_u32<0x140>(mi);
            mi = dpp_min_u32<0x142>(mi);
            mi = dpp_min_u32<0x143>(mi);
            if (lane == 63) atomicMin(&sidx[p], mi);
        }
        __syncthreads();              // barrier 2

        int fi = (int)sidx[p];
        last = fi;
        if (t == 0) {
            out_fps[(size_t)b * NGROUP + g] = (float)fi;
            out_center[((size_t)(b * NGROUP + g)) * 3 + 0] = sxyz[fi*3 + 0];
            out_center[((size_t)(b * NGROUP + g)) * 3 + 1] = sxyz[fi*3 + 1];
            out_center[((size_t)(b * NGROUP + g)) * 3 + 2] = sxyz[fi*3 + 2];
        }
    }
}

// ---------------------------------------------------------------------------
// kNN: one wave/group. Per lane: 128 pts (3 float4 / 4 pts), per-lane top-4
// as sorted u64 keys, then 32 rounds of wave min+pop.
// ---------------------------------------------------------------------------
__global__ __launch_bounds__(256)
void knn_kernel(const float* __restrict__ xyz,
                const float* __restrict__ center,
                float* __restrict__ out_nbhd)
{
    const int lane = threadIdx.x & 63;
    const int gid  = blockIdx.x * 4 + (threadIdx.x >> 6);   // 0..16383
    const int b    = gid >> 9;
    const float* bp = xyz + (size_t)b * NPTS * 3;
    const float4* bp4 = reinterpret_cast<const float4*>(bp);

    const float cx = center[(size_t)gid*3+0];
    const float cy = center[(size_t)gid*3+1];
    const float cz = center[(size_t)gid*3+2];

    unsigned long long kl[4];
    #pragma unroll
    for (int k = 0; k < 4; ++k) kl[k] = ~0ULL;

    for (int c = 0; c < 32; ++c) {
        int f4 = c * 192 + lane * 3;
        float4 a  = bp4[f4+0];
        float4 bq = bp4[f4+1];
        float4 cq = bp4[f4+2];
        int p0 = c * 256 + lane * 4;
        float xs[4] = {a.x, a.w, bq.z, cq.y};
        float ys[4] = {a.y, bq.x, bq.w, cq.z};
        float zs[4] = {a.z, bq.y, cq.x, cq.w};
        #pragma unroll
        for (int k = 0; k < 4; ++k) {
            float dx = xs[k]-cx, dy = ys[k]-cy, dz = zs[k]-cz;
            float d = dx*dx + dy*dy + dz*dz;
            unsigned long long key =
                (((unsigned long long)__float_as_uint(d)) << 32) | (unsigned)(p0 + k);
            if (key < kl[3]) {
                kl[3] = key;
                #pragma unroll
                for (int q = 3; q > 0; --q) {
                    if (kl[q] < kl[q-1]) {
                        unsigned long long tk = kl[q]; kl[q] = kl[q-1]; kl[q-1] = tk;
                    }
                }
            }
        }
    }

    int keep = 0;
    #pragma unroll 1
    for (int r = 0; r < MSIZE; ++r) {
        unsigned long long k = kl[0];
        k = dpp_min_u64<0xB1>(k);
        k = dpp_min_u64<0x4E>(k);
        k = dpp_min_u64<0x141>(k);
        k = dpp_min_u64<0x140>(k);
        {
            unsigned long long o = __shfl_xor(k, 16);
            if (o < k) k = o;
            o = __shfl_xor(k, 32);
            if (o < k) k = o;
        }
        if (lane == r) keep = (int)(unsigned)k;
        if (kl[0] == k) {
            kl[0] = kl[1]; kl[1] = kl[2]; kl[2] = kl[3];
            kl[3] = ~0ULL;
        }
    }

    if (lane < MSIZE) {
        size_t o = ((size_t)gid * MSIZE + lane) * 3;
        float x = bp[keep*3+0], y = bp[keep*3+1], z = bp[keep*3+2];
        out_nbhd[o+0] = x - cx;
        out_nbhd[o+1] = y - cy;
        out_nbhd[o+2] = z - cz;
    }
}

// ---------------------------------------------------------------------------
extern "C" void kernel_launch(void* const* d_in, const int* in_sizes, int n_in,
                              void* d_out, int out_size, void* d_ws, size_t ws_size,
                              hipStream_t stream)
{
    const float* xyz = (const float*)d_in[0];
    float* out        = (float*)d_out;
    float* out_nbhd   = out;                                    // 32*512*32*3
    float* out_center = out + (size_t)BATCH*NGROUP*MSIZE*3;     // 32*512*3
    float* out_fps    = out_center + (size_t)BATCH*NGROUP*3;    // 32*512

    hipFuncSetAttribute(reinterpret_cast<const void*>(fps_kernel),
                        hipFuncAttributeMaxDynamicSharedMemorySize,
                        DYN_LDS_BYTES);

    fps_kernel<<<dim3(BATCH), dim3(FPS_THREADS), DYN_LDS_BYTES, stream>>>(xyz, out_center, out_fps);
    knn_kernel<<<dim3(BATCH*NGROUP/4), dim3(256), 0, stream>>>(xyz, out_center, out_nbhd);
}

// Round 5
// 619.198 us; speedup vs baseline: 1.1389x; 1.1389x over previous
//
#include <hip/hip_runtime.h>
#include <math.h>

#define BATCH  32
#define NPTS   8192
#define NGROUP 512
#define MSIZE  32

#define FPS_THREADS 512
#define SXYZ_FLOATS (NPTS * 3)
#define DYN_LDS_BYTES (SXYZ_FLOATS * 4)

typedef float v2f __attribute__((ext_vector_type(2)));

// ---- DPP helpers (CTRL compile-time const) --------------------------------
// f32 max: bound_ctrl=true -> masked-off lanes read 0; fmax(x,0)=x for x>=0.
template<int CTRL>
__device__ __forceinline__ float dpp_max_f32(float x) {
    int o = __builtin_amdgcn_update_dpp(0, __float_as_int(x), CTRL, 0xF, 0xF, true);
    float f = __int_as_float(o);
    return x > f ? x : f;
}
// u32 min: bcast stages corrupt non-receiving rows to 0, but only lane 63's
// chain is consumed (valid sources all the way) — same scheme as R4, passed.
template<int CTRL>
__device__ __forceinline__ unsigned dpp_min_u32(unsigned x) {
    unsigned o = (unsigned)__builtin_amdgcn_update_dpp(0, (int)x, CTRL, 0xF, 0xF, true);
    return o < x ? o : x;
}
// u64 max over full-permutation ctrls only (every lane has a valid source).
template<int CTRL>
__device__ __forceinline__ unsigned long long dpp_max_u64(unsigned long long k) {
    int lo2 = __builtin_amdgcn_update_dpp(0, (int)(unsigned)k,        CTRL, 0xF, 0xF, true);
    int hi2 = __builtin_amdgcn_update_dpp(0, (int)(unsigned)(k >> 32), CTRL, 0xF, 0xF, true);
    unsigned long long k2 = (((unsigned long long)(unsigned)hi2) << 32) | (unsigned)lo2;
    return k2 > k ? k2 : k;
}
template<int CTRL>
__device__ __forceinline__ unsigned dpp_min_u32_full(unsigned x) {
    unsigned o = (unsigned)__builtin_amdgcn_update_dpp(0, (int)x, CTRL, 0xF, 0xF, true);
    return o < x ? o : x;
}

// ---------------------------------------------------------------------------
// FPS: one block/batch, 512 threads (8 waves, 2/SIMD), 16 pts/thread as
// float2 pairs (v_pk_add/mul_f32 double-rate FP32, per-element bit-exact
// numpy order: (dx^2+dy^2)+dz^2, contract off). Per step, ONE barrier:
//   dist update -> f32 max tree -> f32 DPP wave max -> wmax=readlane63
//   -> in-wave min index among dist==wmax (cmp/sel + u32 tree + u32 DPP)
//   -> lane63 writes u64 (distbits<<32)|~idx partial -> barrier
//   -> all lanes read partial[lane&7], 3-stage full-perm u64 max butterfly
//      (all lanes end uniform) -> fi = ~lo32.
// Exact np.argmax first-occurrence semantics incl. cross-wave ties.
// ---------------------------------------------------------------------------
__global__ __launch_bounds__(FPS_THREADS, 2)
void fps_kernel(const float* __restrict__ xyz,
                float* __restrict__ out_center,
                float* __restrict__ out_fps)
{
#pragma clang fp contract(off)
    extern __shared__ float sxyz[];                        // [24576]
    __shared__ unsigned long long partial[2][8];

    const int b    = blockIdx.x;
    const int t    = threadIdx.x;
    const int lane = t & 63;
    const int wid  = t >> 6;
    const float* bp = xyz + (size_t)b * NPTS * 3;
    const float4* bp4 = reinterpret_cast<const float4*>(bp);
    float4* s4 = reinterpret_cast<float4*>(sxyz);

    // thread t owns pts gidx = c*2048 + t*4 + k, c in [0,4), k in [0,4)
    // pair j = c*2 + (k>>1); element h = k&1.
    v2f px2[8], py2[8], pz2[8], dist2[8];
    unsigned idxv[16];
    #pragma unroll
    for (int c = 0; c < 4; ++c) {
        int f4 = c * 1536 + t * 3;
        float4 A = bp4[f4 + 0];
        float4 B = bp4[f4 + 1];
        float4 C = bp4[f4 + 2];
        s4[f4 + 0] = A; s4[f4 + 1] = B; s4[f4 + 2] = C;
        int j0 = c * 2, j1 = c * 2 + 1;
        px2[j0] = (v2f){A.x, A.w};  py2[j0] = (v2f){A.y, B.x};  pz2[j0] = (v2f){A.z, B.y};
        px2[j1] = (v2f){B.z, C.y};  py2[j1] = (v2f){B.w, C.z};  pz2[j1] = (v2f){C.x, C.w};
        dist2[j0] = (v2f){INFINITY, INFINITY};
        dist2[j1] = (v2f){INFINITY, INFINITY};
        #pragma unroll
        for (int k = 0; k < 4; ++k)
            idxv[c*4 + k] = (unsigned)(c * 2048 + t * 4 + k);
    }
    __syncthreads();   // sxyz visible

    if (t == 0) {
        out_fps[(size_t)b * NGROUP] = 0.0f;
        out_center[(size_t)(b * NGROUP) * 3 + 0] = sxyz[0];
        out_center[(size_t)(b * NGROUP) * 3 + 1] = sxyz[1];
        out_center[(size_t)(b * NGROUP) * 3 + 2] = sxyz[2];
    }

    int last = 0;
    for (int g = 1; g < NGROUP; ++g) {
        const int p = g & 1;
        float lx = sxyz[last*3 + 0];     // broadcast LDS reads
        float ly = sxyz[last*3 + 1];
        float lz = sxyz[last*3 + 2];

        // packed dist update: per element (dx*dx + dy*dy) + dz*dz, then min
        #pragma unroll
        for (int j = 0; j < 8; ++j) {
            v2f dx = px2[j] - lx;
            v2f dy = py2[j] - ly;
            v2f dz = pz2[j] - lz;
            v2f t1 = dx * dx;
            v2f t2 = dy * dy;
            v2f t3 = dz * dz;
            v2f s  = t1 + t2;
            v2f d  = s + t3;
            dist2[j] = __builtin_elementwise_min(dist2[j], d);
        }
        // per-thread max (exact, order-free)
        v2f mm = dist2[0];
        #pragma unroll
        for (int j = 1; j < 8; ++j) mm = __builtin_elementwise_max(mm, dist2[j]);
        float m = fmaxf(mm.x, mm.y);
        // f32 DPP wave max -> lane 63, broadcast via readlane
        m = dpp_max_f32<0xB1>(m);     // quad_perm xor1
        m = dpp_max_f32<0x4E>(m);     // quad_perm xor2
        m = dpp_max_f32<0x141>(m);    // row_half_mirror
        m = dpp_max_f32<0x140>(m);    // row_mirror
        m = dpp_max_f32<0x142>(m);    // row_bcast15
        m = dpp_max_f32<0x143>(m);    // row_bcast31
        float wmax = __int_as_float(__builtin_amdgcn_readlane(__float_as_int(m), 63));

        // in-wave min index among dist==wmax (>=1 match guaranteed)
        unsigned c0[16];
        #pragma unroll
        for (int j = 0; j < 8; ++j) {
            c0[2*j+0] = (dist2[j].x == wmax) ? idxv[2*j+0] : 0xFFFFFFFFu;
            c0[2*j+1] = (dist2[j].y == wmax) ? idxv[2*j+1] : 0xFFFFFFFFu;
        }
        #pragma unroll
        for (int s = 8; s >= 1; s >>= 1)
            #pragma unroll
            for (int i = 0; i < s; ++i)
                c0[i] = c0[i] < c0[i+s] ? c0[i] : c0[i+s];
        unsigned mi = c0[0];
        mi = dpp_min_u32<0xB1>(mi);
        mi = dpp_min_u32<0x4E>(mi);
        mi = dpp_min_u32<0x141>(mi);
        mi = dpp_min_u32<0x140>(mi);
        mi = dpp_min_u32<0x142>(mi);
        mi = dpp_min_u32<0x143>(mi);   // lane 63 holds wave min idx
        if (lane == 63) {
            unsigned long long key =
                (((unsigned long long)__float_as_uint(wmax)) << 32) | (unsigned)~mi;
            partial[p][wid] = key;
        }
        __syncthreads();              // the ONE barrier

        // lane-parallel block reduce: every lane reads one of 8 partials
        // (broadcast groups, conflict-free), 3-stage full-perm u64 butterfly
        // -> all lanes uniform = (gmax, min idx among ties).
        unsigned long long kq = partial[p][lane & 7];
        kq = dpp_max_u64<0xB1>(kq);
        kq = dpp_max_u64<0x4E>(kq);
        kq = dpp_max_u64<0x141>(kq);
        int fi = (int)(~(unsigned)kq);
        last = fi;
        if (t == 0) {
            out_fps[(size_t)b * NGROUP + g] = (float)fi;
            out_center[((size_t)(b * NGROUP + g)) * 3 + 0] = sxyz[fi*3 + 0];
            out_center[((size_t)(b * NGROUP + g)) * 3 + 1] = sxyz[fi*3 + 1];
            out_center[((size_t)(b * NGROUP + g)) * 3 + 2] = sxyz[fi*3 + 2];
        }
    }
}

// ---------------------------------------------------------------------------
// kNN: one wave/group. Per lane: 128 pts (3 float4 / 4 pts, packed f32 dist),
// per-lane top-4 as sorted u32 keys (distbits&~0x1FFF | idx13 — truncation
// only perturbs rank among near-equal dists; error bounded far below the
// 163.84 threshold on outputs 0/1), then 32 rounds of wave min+pop with
// full-valid u32 butterfly (4 DPP stages + 2 shfl).
// ---------------------------------------------------------------------------
__global__ __launch_bounds__(256)
void knn_kernel(const float* __restrict__ xyz,
                const float* __restrict__ center,
                float* __restrict__ out_nbhd)
{
    const int lane = threadIdx.x & 63;
    const int gid  = blockIdx.x * 4 + (threadIdx.x >> 6);   // 0..16383
    const int b    = gid >> 9;
    const float* bp = xyz + (size_t)b * NPTS * 3;
    const float4* bp4 = reinterpret_cast<const float4*>(bp);

    const float cx = center[(size_t)gid*3+0];
    const float cy = center[(size_t)gid*3+1];
    const float cz = center[(size_t)gid*3+2];

    unsigned kl[4];
    #pragma unroll
    for (int k = 0; k < 4; ++k) kl[k] = 0xFFFFFFFFu;

    for (int c = 0; c < 32; ++c) {
        int f4 = c * 192 + lane * 3;
        float4 a  = bp4[f4+0];
        float4 bq = bp4[f4+1];
        float4 cq = bp4[f4+2];
        unsigned p0 = (unsigned)(c * 256 + lane * 4);
        v2f xA = (v2f){a.x,  a.w},  yA = (v2f){a.y,  bq.x}, zA = (v2f){a.z,  bq.y};
        v2f xB = (v2f){bq.z, cq.y}, yB = (v2f){bq.w, cq.z}, zB = (v2f){cq.x, cq.w};
        v2f dxA = xA - cx, dyA = yA - cy, dzA = zA - cz;
        v2f dxB = xB - cx, dyB = yB - cy, dzB = zB - cz;
        v2f dA = dxA*dxA + dyA*dyA + dzA*dzA;
        v2f dB = dxB*dxB + dyB*dyB + dzB*dzB;
        float ds[4] = {dA.x, dA.y, dB.x, dB.y};
        #pragma unroll
        for (int k = 0; k < 4; ++k) {
            unsigned key = (__float_as_uint(ds[k]) & 0xFFFFE000u) | (p0 + k);
            if (key < kl[3]) {
                kl[3] = key;
                #pragma unroll
                for (int q = 3; q > 0; --q) {
                    if (kl[q] < kl[q-1]) {
                        unsigned tk = kl[q]; kl[q] = kl[q-1]; kl[q-1] = tk;
                    }
                }
            }
        }
    }

    int keep = 0;
    #pragma unroll 1
    for (int r = 0; r < MSIZE; ++r) {
        unsigned k = kl[0];
        k = dpp_min_u32_full<0xB1>(k);     // xor1
        k = dpp_min_u32_full<0x4E>(k);     // xor2
        k = dpp_min_u32_full<0x141>(k);    // half mirror (xor4 after quads)
        k = dpp_min_u32_full<0x140>(k);    // mirror (xor8) -> rows of 16 uniform
        {
            unsigned o = __shfl_xor(k, 16);
            k = o < k ? o : k;
            o = __shfl_xor(k, 32);
            k = o < k ? o : k;
        }
        if (lane == r) keep = (int)(k & 0x1FFFu);
        if (kl[0] == k) {                   // unique (idx embedded)
            kl[0] = kl[1]; kl[1] = kl[2]; kl[2] = kl[3];
            kl[3] = 0xFFFFFFFFu;
        }
    }

    if (lane < MSIZE) {
        size_t o = ((size_t)gid * MSIZE + lane) * 3;
        float x = bp[keep*3+0], y = bp[keep*3+1], z = bp[keep*3+2];
        out_nbhd[o+0] = x - cx;
        out_nbhd[o+1] = y - cy;
        out_nbhd[o+2] = z - cz;
    }
}

// ---------------------------------------------------------------------------
extern "C" void kernel_launch(void* const* d_in, const int* in_sizes, int n_in,
                              void* d_out, int out_size, void* d_ws, size_t ws_size,
                              hipStream_t stream)
{
    const float* xyz = (const float*)d_in[0];
    float* out        = (float*)d_out;
    float* out_nbhd   = out;                                    // 32*512*32*3
    float* out_center = out + (size_t)BATCH*NGROUP*MSIZE*3;     // 32*512*3
    float* out_fps    = out_center + (size_t)BATCH*NGROUP*3;    // 32*512

    hipFuncSetAttribute(reinterpret_cast<const void*>(fps_kernel),
                        hipFuncAttributeMaxDynamicSharedMemorySize,
                        DYN_LDS_BYTES);

    fps_kernel<<<dim3(BATCH), dim3(FPS_THREADS), DYN_LDS_BYTES, stream>>>(xyz, out_center, out_fps);
    knn_kernel<<<dim3(BATCH*NGROUP/4), dim3(256), 0, stream>>>(xyz, out_center, out_nbhd);
}

// Round 6
// 576.739 us; speedup vs baseline: 1.2227x; 1.0736x over previous
//
#include <hip/hip_runtime.h>
#include <math.h>

#define BATCH  32
#define NPTS   8192
#define NGROUP 512
#define MSIZE  32

#define FPS_THREADS 512
#define SXYZ_FLOATS (NPTS * 3)
#define DYN_LDS_BYTES (SXYZ_FLOATS * 4)

typedef float v2f __attribute__((ext_vector_type(2)));

// ---- DPP helpers (CTRL compile-time const) --------------------------------
// f32 max: bound_ctrl=true -> masked-off lanes read 0; fmax(x,0)=x for x>=0.
template<int CTRL>
__device__ __forceinline__ float dpp_max_f32(float x) {
    int o = __builtin_amdgcn_update_dpp(0, __float_as_int(x), CTRL, 0xF, 0xF, true);
    float f = __int_as_float(o);
    return x > f ? x : f;
}
template<int CTRL>
__device__ __forceinline__ unsigned dpp_min_u32_full(unsigned x) {
    unsigned o = (unsigned)__builtin_amdgcn_update_dpp(0, (int)x, CTRL, 0xF, 0xF, true);
    return o < x ? o : x;
}

// ---------------------------------------------------------------------------
// FPS: one block/batch, 512 threads (8 waves, 2/SIMD), 16 pts/thread as v2f
// pairs (packed f32 math, per-element bit-exact numpy order: (dx^2+dy^2)+dz^2,
// contract off). Ownership CONTIGUOUS: thread t owns [16t, 16t+16) so
// (wave,lane,j) lexicographic == global index order. Per step, ONE barrier:
//   dist update -> per-thread max m_t -> 6-stage f32 DPP -> wmax=readlane63
//   -> ballot(m_t==wmax) -> lowest candidate lane l (s_ff1)
//   -> all lanes: lj = lowest j with d[j]==wmax (cmp/sel chain); idx=(t<<4)|lj
//   -> widx = readlane(idx, l)   [wave winner, exact first-occurrence]
//   -> lane63: ds_max_u64(gkey[g%3], (wmaxbits<<32)|~widx)
//   -> barrier -> all read gkey (broadcast b64) -> fi = ~lo32.
// gkey triple-buffered; slot (g+1)%3 reset in step g (race-free: its last
// readers passed barrier(g-1) before the reset, next writers start after
// barrier(g)). Exact np.argmax first-occurrence semantics incl. ties.
// ---------------------------------------------------------------------------
__global__ __launch_bounds__(FPS_THREADS, 2)
void fps_kernel(const float* __restrict__ xyz,
                float* __restrict__ out_center,
                float* __restrict__ out_fps)
{
#pragma clang fp contract(off)
    extern __shared__ float sxyz[];                        // [24576]
    __shared__ unsigned long long gkey[3];

    const int b    = blockIdx.x;
    const int t    = threadIdx.x;
    const int lane = t & 63;
    const float* bp = xyz + (size_t)b * NPTS * 3;
    const float4* bp4 = reinterpret_cast<const float4*>(bp);
    float4* s4 = reinterpret_cast<float4*>(sxyz);

    // contiguous ownership: thread t owns points 16t..16t+15 (48 floats,
    // 12 float4). Stage into LDS with the same reads.
    v2f px2[8], py2[8], pz2[8], dist2[8];
    {
        float f[48];
        #pragma unroll
        for (int q = 0; q < 12; ++q) {
            float4 v = bp4[t * 12 + q];
            s4[t * 12 + q] = v;
            f[q*4+0] = v.x; f[q*4+1] = v.y; f[q*4+2] = v.z; f[q*4+3] = v.w;
        }
        #pragma unroll
        for (int j = 0; j < 8; ++j) {
            px2[j] = (v2f){f[6*j+0], f[6*j+3]};
            py2[j] = (v2f){f[6*j+1], f[6*j+4]};
            pz2[j] = (v2f){f[6*j+2], f[6*j+5]};
            dist2[j] = (v2f){INFINITY, INFINITY};
        }
    }
    if (t == 0) { gkey[0] = 0; gkey[1] = 0; gkey[2] = 0; }
    __syncthreads();   // sxyz + gkey visible

    if (t == 0) {
        out_fps[(size_t)b * NGROUP] = 0.0f;
        out_center[(size_t)(b * NGROUP) * 3 + 0] = sxyz[0];
        out_center[(size_t)(b * NGROUP) * 3 + 1] = sxyz[1];
        out_center[(size_t)(b * NGROUP) * 3 + 2] = sxyz[2];
    }

    int last = 0;
    for (int g = 1; g < NGROUP; ++g) {
        const int slot = g % 3;
        const int nxt  = (g + 1) % 3;
        float lx = sxyz[last*3 + 0];     // broadcast LDS reads
        float ly = sxyz[last*3 + 1];
        float lz = sxyz[last*3 + 2];

        // packed dist update: per element (dx*dx + dy*dy) + dz*dz, then min
        #pragma unroll
        for (int j = 0; j < 8; ++j) {
            v2f dx = px2[j] - lx;
            v2f dy = py2[j] - ly;
            v2f dz = pz2[j] - lz;
            v2f t1 = dx * dx;
            v2f t2 = dy * dy;
            v2f t3 = dz * dz;
            v2f s  = t1 + t2;
            v2f d  = s + t3;
            dist2[j] = __builtin_elementwise_min(dist2[j], d);
        }
        // per-thread max (exact, order-free)
        v2f mm0 = __builtin_elementwise_max(dist2[0], dist2[1]);
        v2f mm1 = __builtin_elementwise_max(dist2[2], dist2[3]);
        v2f mm2 = __builtin_elementwise_max(dist2[4], dist2[5]);
        v2f mm3 = __builtin_elementwise_max(dist2[6], dist2[7]);
        v2f mma = __builtin_elementwise_max(mm0, mm1);
        v2f mmb = __builtin_elementwise_max(mm2, mm3);
        v2f mmc = __builtin_elementwise_max(mma, mmb);
        float m_t = fmaxf(mmc.x, mmc.y);

        // wave max via DPP -> wmax (uniform, sgpr)
        float m = m_t;
        m = dpp_max_f32<0xB1>(m);     // quad_perm xor1
        m = dpp_max_f32<0x4E>(m);     // quad_perm xor2
        m = dpp_max_f32<0x141>(m);    // row_half_mirror
        m = dpp_max_f32<0x140>(m);    // row_mirror
        m = dpp_max_f32<0x142>(m);    // row_bcast15
        m = dpp_max_f32<0x143>(m);    // row_bcast31
        float wmax = __int_as_float(__builtin_amdgcn_readlane(__float_as_int(m), 63));

        // lowest candidate lane (contiguous ownership => lane order = idx order)
        unsigned long long mask = __ballot(m_t == wmax);
        int l = __ffsll((long long)mask) - 1;

        // each lane: lowest j with d[j]==wmax (descending select chain)
        unsigned lj = 0;
        #pragma unroll
        for (int j = 15; j >= 0; --j) {
            float dj = (j & 1) ? dist2[j >> 1].y : dist2[j >> 1].x;
            lj = (dj == wmax) ? (unsigned)j : lj;
        }
        unsigned idx = ((unsigned)t << 4) | lj;
        unsigned widx = (unsigned)__builtin_amdgcn_readlane((int)idx, l);

        if (lane == 63) {
            unsigned long long key =
                (((unsigned long long)__float_as_uint(wmax)) << 32) | (unsigned)~widx;
            atomicMax(&gkey[slot], key);
            if (t == 63) gkey[nxt] = 0;   // reset slot for step g+1 (pre-barrier)
        }
        __syncthreads();                  // the ONE barrier

        unsigned long long kq = gkey[slot];   // broadcast b64 read
        int fi = (int)(~(unsigned)kq);
        last = fi;
        if (t == 0) {
            out_fps[(size_t)b * NGROUP + g] = (float)fi;
            out_center[((size_t)(b * NGROUP + g)) * 3 + 0] = sxyz[fi*3 + 0];
            out_center[((size_t)(b * NGROUP + g)) * 3 + 1] = sxyz[fi*3 + 1];
            out_center[((size_t)(b * NGROUP + g)) * 3 + 2] = sxyz[fi*3 + 2];
        }
    }
}

// ---------------------------------------------------------------------------
// kNN: one wave/group. Per lane: 128 pts (3 float4 / 4 pts, packed f32 dist),
// per-lane top-4 as sorted u32 keys (distbits&~0x1FFF | idx13 — truncation
// only perturbs rank among near-equal dists; bounded far below the 163.84
// threshold on outputs 0/1), then 32 rounds of wave min+pop.
// ---------------------------------------------------------------------------
__global__ __launch_bounds__(256)
void knn_kernel(const float* __restrict__ xyz,
                const float* __restrict__ center,
                float* __restrict__ out_nbhd)
{
    const int lane = threadIdx.x & 63;
    const int gid  = blockIdx.x * 4 + (threadIdx.x >> 6);   // 0..16383
    const int b    = gid >> 9;
    const float* bp = xyz + (size_t)b * NPTS * 3;
    const float4* bp4 = reinterpret_cast<const float4*>(bp);

    const float cx = center[(size_t)gid*3+0];
    const float cy = center[(size_t)gid*3+1];
    const float cz = center[(size_t)gid*3+2];

    unsigned kl[4];
    #pragma unroll
    for (int k = 0; k < 4; ++k) kl[k] = 0xFFFFFFFFu;

    for (int c = 0; c < 32; ++c) {
        int f4 = c * 192 + lane * 3;
        float4 a  = bp4[f4+0];
        float4 bq = bp4[f4+1];
        float4 cq = bp4[f4+2];
        unsigned p0 = (unsigned)(c * 256 + lane * 4);
        v2f xA = (v2f){a.x,  a.w},  yA = (v2f){a.y,  bq.x}, zA = (v2f){a.z,  bq.y};
        v2f xB = (v2f){bq.z, cq.y}, yB = (v2f){bq.w, cq.z}, zB = (v2f){cq.x, cq.w};
        v2f dxA = xA - cx, dyA = yA - cy, dzA = zA - cz;
        v2f dxB = xB - cx, dyB = yB - cy, dzB = zB - cz;
        v2f dA = dxA*dxA + dyA*dyA + dzA*dzA;
        v2f dB = dxB*dxB + dyB*dyB + dzB*dzB;
        float ds[4] = {dA.x, dA.y, dB.x, dB.y};
        #pragma unroll
        for (int k = 0; k < 4; ++k) {
            unsigned key = (__float_as_uint(ds[k]) & 0xFFFFE000u) | (p0 + k);
            if (key < kl[3]) {
                kl[3] = key;
                #pragma unroll
                for (int q = 3; q > 0; --q) {
                    if (kl[q] < kl[q-1]) {
                        unsigned tk = kl[q]; kl[q] = kl[q-1]; kl[q-1] = tk;
                    }
                }
            }
        }
    }

    int keep = 0;
    #pragma unroll 1
    for (int r = 0; r < MSIZE; ++r) {
        unsigned k = kl[0];
        k = dpp_min_u32_full<0xB1>(k);     // xor1
        k = dpp_min_u32_full<0x4E>(k);     // xor2
        k = dpp_min_u32_full<0x141>(k);    // half mirror
        k = dpp_min_u32_full<0x140>(k);    // mirror -> rows of 16 uniform
        {
            unsigned o = __shfl_xor(k, 16);
            k = o < k ? o : k;
            o = __shfl_xor(k, 32);
            k = o < k ? o : k;
        }
        if (lane == r) keep = (int)(k & 0x1FFFu);
        if (kl[0] == k) {                   // unique (idx embedded)
            kl[0] = kl[1]; kl[1] = kl[2]; kl[2] = kl[3];
            kl[3] = 0xFFFFFFFFu;
        }
    }

    if (lane < MSIZE) {
        size_t o = ((size_t)gid * MSIZE + lane) * 3;
        float x = bp[keep*3+0], y = bp[keep*3+1], z = bp[keep*3+2];
        out_nbhd[o+0] = x - cx;
        out_nbhd[o+1] = y - cy;
        out_nbhd[o+2] = z - cz;
    }
}

// ---------------------------------------------------------------------------
extern "C" void kernel_launch(void* const* d_in, const int* in_sizes, int n_in,
                              void* d_out, int out_size, void* d_ws, size_t ws_size,
                              hipStream_t stream)
{
    const float* xyz = (const float*)d_in[0];
    float* out        = (float*)d_out;
    float* out_nbhd   = out;                                    // 32*512*32*3
    float* out_center = out + (size_t)BATCH*NGROUP*MSIZE*3;     // 32*512*3
    float* out_fps    = out_center + (size_t)BATCH*NGROUP*3;    // 32*512

    hipFuncSetAttribute(reinterpret_cast<const void*>(fps_kernel),
                        hipFuncAttributeMaxDynamicSharedMemorySize,
                        DYN_LDS_BYTES);

    fps_kernel<<<dim3(BATCH), dim3(FPS_THREADS), DYN_LDS_BYTES, stream>>>(xyz, out_center, out_fps);
    knn_kernel<<<dim3(BATCH*NGROUP/4), dim3(256), 0, stream>>>(xyz, out_center, out_nbhd);
}